// Round 5
// baseline (375.513 us; speedup 1.0000x reference)
//
#include <hip/hip_runtime.h>
#include <hip/hip_bf16.h>

#define N_NODES 50000
#define D_IN 128
#define D_OUT 64
#define N_ETYPES 3
#define E_PER_ETYPE 500000
#define N_EDGES (N_ETYPES * E_PER_ETYPE)
#define CAP1 16    // primary bucket: one 64B line per (etype,node)
#define CAP2 32    // spill (deg>16: ~2.7% of cells; P(deg>48)~1e-19)
#define EPB 2048   // edges per claimable chunk
#define NCHUNK ((N_EDGES + EPB - 1) / EPB)   // 733
#define NSLICE 8

static __device__ __forceinline__ unsigned short f2bf(float f) {
    unsigned int x = __float_as_uint(f);
    unsigned int lsb = (x >> 16) & 1u;
    x += 0x7fffu + lsb;          // round-to-nearest-even
    return (unsigned short)(x >> 16);
}

// feat (fp32) -> featbf (bf16), 4 elems/thread.
__global__ __launch_bounds__(256) void convert_kernel(
    const float* __restrict__ feat,
    unsigned short* __restrict__ featbf)
{
    int i = blockIdx.x * 256 + threadIdx.x;
    const float4* f4 = (const float4*)feat;
    float4 v = f4[i];
    ushort4 o;
    o.x = f2bf(v.x); o.y = f2bf(v.y); o.z = f2bf(v.z); o.w = f2bf(v.w);
    ((ushort4*)featbf)[i] = o;
}

// Runtime-XCD-sliced binning. R3/R4 evidence: WRITE_SIZE=87MB ~= 9x bucket
// footprint -> each bucket line flushed as partial-dirty from ~8 XCDs; static
// blockIdx%8 slicing (R4) did NOT fix it => blockIdx->XCD mapping assumption
// wrong. Now: block reads its REAL XCC id and claims chunks from that slice's
// queue (atomic exactly-once), then steals other slices (correct under ANY
// block->XCD mapping; getreg value only affects locality, not correctness).
__global__ __launch_bounds__(256) void fill_kernel(
    const int* __restrict__ edge_index,
    int* __restrict__ bucket1,
    int* __restrict__ spill,
    int* __restrict__ cnt,
    int* __restrict__ queues)
{
    __shared__ int sChunk;
    // HW_REG_XCC_ID = id 20, offset 0, width 4  (mask &7; wrong value is
    // only a locality miss thanks to the steal pass)
    int myxcc = __builtin_amdgcn_s_getreg((3 << 11) | 20) & (NSLICE - 1);

    #pragma unroll 1
    for (int k = 0; k < NSLICE; k++) {
        int s = (myxcc + k) & (NSLICE - 1);
        // cheap pre-check: stale read just means we do the atomic anyway
        if (*(volatile int*)(queues + s) >= NCHUNK) continue;
        while (true) {
            if (threadIdx.x == 0) sChunk = atomicAdd(queues + s, 1);
            __syncthreads();
            int c = sChunk;
            __syncthreads();
            if (c >= NCHUNK) break;
            int e0 = c * EPB + threadIdx.x;
            #pragma unroll
            for (int it = 0; it < EPB / 256; it++) {
                int e = e0 + it * 256;
                if (e >= N_EDGES) break;
                int t  = e / E_PER_ETYPE;
                int ei = e - t * E_PER_ETYPE;
                const int* base = edge_index + (long long)t * 2 * E_PER_ETYPE;
                int dst = base[E_PER_ETYPE + ei];          // coalesced
                if (((dst >> 4) & (NSLICE - 1)) != s) continue;
                int src = base[ei];
                int cell = t * N_NODES + dst;
                int pos = atomicAdd(cnt + cell, 1);
                if (pos < CAP1)
                    bucket1[(long long)cell * CAP1 + pos] = src;
                else if (pos < CAP1 + CAP2)
                    spill[(long long)cell * CAP2 + (pos - CAP1)] = src;
            }
        }
    }
}

// Fused gather + epilogue + linear. 512 thr = 8 waves = 8 nodes/block.
// Wave per node; lane l owns dims [2l,2l+1]. deg/bucket rows preloaded for
// all 3 etypes; gather loop unrolled x4 so 4 independent 256B row loads are
// in flight (R4 showed latency-bound: 15% HBM, 46% VALU).
__global__ __launch_bounds__(512) void gather_linear_kernel(
    const float* __restrict__ feat,
    const unsigned short* __restrict__ featbf,
    const float* __restrict__ Wg,
    const float* __restrict__ bg,
    const int* __restrict__ bucket1,
    const int* __restrict__ spill,
    const int* __restrict__ cnt,
    float* __restrict__ out)
{
    __shared__ float Ws[D_IN * D_OUT];   // 32 KB
    __shared__ float bs[D_OUT];
    __shared__ float hs[8][D_IN];        // 4 KB

    int tid = threadIdx.x;
    for (int i = tid; i < D_IN * D_OUT; i += 512) Ws[i] = Wg[i];
    if (tid < D_OUT) bs[tid] = bg[tid];

    int wave = tid >> 6;
    int lane = tid & 63;
    int n = blockIdx.x * 8 + wave;       // 6250*8 == 50000 exactly

    float2 f = ((const float2*)feat)[(long long)n * 64 + lane];  // fp32 residual

    int deg[N_ETYPES], idx[N_ETYPES];
    #pragma unroll
    for (int t = 0; t < N_ETYPES; t++) {
        int cell = t * N_NODES + n;
        int dg = cnt[cell];                       // wave-uniform
        int id = 0;
        if (lane < CAP1) id = bucket1[(long long)cell * CAP1 + lane];
        else if (lane < CAP1 + CAP2 && dg > CAP1)
            id = spill[(long long)cell * CAP2 + (lane - CAP1)];
        deg[t] = dg; idx[t] = id;
    }

    const unsigned int* fbl = (const unsigned int*)featbf + lane; // row = 64 dwords
    float sx = 0.0f, sy = 0.0f;
    #pragma unroll
    for (int t = 0; t < N_ETYPES; t++) {
        int d = (deg[t] < CAP1 + CAP2) ? deg[t] : (CAP1 + CAP2);
        float ax = 0.0f, ay = 0.0f;
        int j = 0;
        for (; j + 4 <= d; j += 4) {
            int s0 = __shfl(idx[t], j);
            int s1 = __shfl(idx[t], j + 1);
            int s2 = __shfl(idx[t], j + 2);
            int s3 = __shfl(idx[t], j + 3);
            unsigned int p0 = fbl[(long long)s0 * 64];
            unsigned int p1 = fbl[(long long)s1 * 64];
            unsigned int p2 = fbl[(long long)s2 * 64];
            unsigned int p3 = fbl[(long long)s3 * 64];
            ax += __uint_as_float(p0 << 16); ay += __uint_as_float(p0 & 0xffff0000u);
            ax += __uint_as_float(p1 << 16); ay += __uint_as_float(p1 & 0xffff0000u);
            ax += __uint_as_float(p2 << 16); ay += __uint_as_float(p2 & 0xffff0000u);
            ax += __uint_as_float(p3 << 16); ay += __uint_as_float(p3 & 0xffff0000u);
        }
        for (; j < d; j++) {
            int s0 = __shfl(idx[t], j);
            unsigned int p0 = fbl[(long long)s0 * 64];
            ax += __uint_as_float(p0 << 16); ay += __uint_as_float(p0 & 0xffff0000u);
        }
        float inv = 1.0f / (float)((deg[t] > 0) ? deg[t] : 1);
        sx += tanhf(ax * inv);
        sy += tanhf(ay * inv);
    }
    float2 hv;
    hv.x = tanhf(f.x + 0.5f * sx);
    hv.y = tanhf(f.y + 0.5f * sy);
    ((float2*)hs[wave])[lane] = hv;
    __syncthreads();

    float acc = bs[lane];
    #pragma unroll 8
    for (int d = 0; d < D_IN; d++)
        acc += hs[wave][d] * Ws[d * D_OUT + lane];   // broadcast + stride-1: conflict-free
    out[(long long)n * D_OUT + lane] = acc;
}

extern "C" void kernel_launch(void* const* d_in, const int* in_sizes, int n_in,
                              void* d_out, int out_size, void* d_ws, size_t ws_size,
                              hipStream_t stream) {
    const float* feat = (const float*)d_in[0];
    const float* W    = (const float*)d_in[1];
    const float* b    = (const float*)d_in[2];
    const int* edge_index = (const int*)d_in[3];
    float* out = (float*)d_out;

    size_t featbf_bytes  = (size_t)N_NODES * D_IN * sizeof(unsigned short);      // 12.8 MB
    size_t bucket1_bytes = (size_t)N_ETYPES * N_NODES * CAP1 * sizeof(int);      //  9.6 MB
    size_t spill_bytes   = (size_t)N_ETYPES * N_NODES * CAP2 * sizeof(int);      // 19.2 MB
    size_t cnt_bytes     = (size_t)N_ETYPES * N_NODES * sizeof(int);             //  0.6 MB
    size_t queue_bytes   = NSLICE * sizeof(int);
    if (ws_size < featbf_bytes + bucket1_bytes + spill_bytes + cnt_bytes + queue_bytes)
        return;  // sentinel: out stays 0 (absmax would read 1.898)

    unsigned short* featbf = (unsigned short*)d_ws;
    int* bucket1 = (int*)((char*)d_ws + featbf_bytes);
    int* spill   = (int*)((char*)d_ws + featbf_bytes + bucket1_bytes);
    int* cnt     = (int*)((char*)d_ws + featbf_bytes + bucket1_bytes + spill_bytes);
    int* queues  = (int*)((char*)cnt + cnt_bytes);

    hipMemsetAsync(cnt, 0, cnt_bytes + queue_bytes, stream);

    convert_kernel<<<(N_NODES * D_IN / 4) / 256, 256, 0, stream>>>(feat, featbf);

    fill_kernel<<<1024, 256, 0, stream>>>(edge_index, bucket1, spill, cnt, queues);

    gather_linear_kernel<<<N_NODES / 8, 512, 0, stream>>>(
        feat, featbf, W, b, bucket1, spill, cnt, out);
}

// Round 6
// 282.061 us; speedup vs baseline: 1.3313x; 1.3313x over previous
//
#include <hip/hip_runtime.h>
#include <hip/hip_bf16.h>

#define N_NODES 50000
#define D_IN 128
#define D_OUT 64
#define N_ETYPES 3
#define E_PER_ETYPE 500000
#define N_EDGES (N_ETYPES * E_PER_ETYPE)
#define CAP1 16   // primary bucket: 32B (ushort) per cell
#define CAP2 32   // spill (deg>16: ~2.6% of cells; P(deg>48)~1e-19)

static __device__ __forceinline__ unsigned short f2bf(float f) {
    unsigned int x = __float_as_uint(f);
    unsigned int lsb = (x >> 16) & 1u;
    x += 0x7fffu + lsb;          // round-to-nearest-even
    return (unsigned short)(x >> 16);
}

// feat (fp32) -> featbf (bf16), 4 elems/thread.
__global__ __launch_bounds__(256) void convert_kernel(
    const float* __restrict__ feat,
    unsigned short* __restrict__ featbf)
{
    int i = blockIdx.x * 256 + threadIdx.x;
    const float4* f4 = (const float4*)feat;
    float4 v = f4[i];
    ushort4 o;
    o.x = f2bf(v.x); o.y = f2bf(v.y); o.z = f2bf(v.z); o.w = f2bf(v.w);
    ((ushort4*)featbf)[i] = o;
}

// R3's proven flat one-pass binning (R5's work-claiming REGRESSED: 196us,
// serialization > locality win). ushort payload halves the scattered-write
// footprint: hot set ~5.4MB so x8 XCD duplication ~ fits aggregate L2.
__global__ __launch_bounds__(256) void fill_kernel(
    const int* __restrict__ edge_index,
    unsigned short* __restrict__ bucket1,
    unsigned short* __restrict__ spill,
    int* __restrict__ cnt)
{
    int gid = blockIdx.x * 256 + threadIdx.x;
    if (gid >= N_EDGES) return;
    int t  = gid / E_PER_ETYPE;
    int ei = gid - t * E_PER_ETYPE;
    const int* base = edge_index + (long long)t * 2 * E_PER_ETYPE;
    int src = base[ei];                 // coalesced
    int dst = base[E_PER_ETYPE + ei];   // coalesced
    int cell = t * N_NODES + dst;
    int pos = atomicAdd(cnt + cell, 1);
    if (pos < CAP1)
        bucket1[(long long)cell * CAP1 + pos] = (unsigned short)src;
    else if (pos < CAP1 + CAP2)
        spill[(long long)cell * CAP2 + (pos - CAP1)] = (unsigned short)src;
}

// Fused gather + epilogue + linear. 512 thr = 8 waves = 8 nodes/block.
// NEW: 4-row-parallel subgroups. Wave = 4 subgroups x 16 lanes; subgroup s
// reads row j+s as uint4 (8 bf16 dims/lane) -> 4 independent 256B gathers in
// flight per iteration, 1/4 the chain length (R4 was latency-bound: 15% HBM,
// serial shfl->load->add). Cross-subgroup reduce (2 x shfl_xor) BEFORE the
// per-etype tanh(mean) nonlinearity.
__global__ __launch_bounds__(512) void gather_linear_kernel(
    const float* __restrict__ feat,
    const unsigned short* __restrict__ featbf,
    const float* __restrict__ Wg,
    const float* __restrict__ bg,
    const unsigned short* __restrict__ bucket1,
    const unsigned short* __restrict__ spill,
    const int* __restrict__ cnt,
    float* __restrict__ out)
{
    __shared__ float Ws[D_IN * D_OUT];   // 32 KB
    __shared__ float bs[D_OUT];
    __shared__ float hs[8][D_IN];        // 4 KB

    int tid = threadIdx.x;
    for (int i = tid; i < D_IN * D_OUT; i += 512) Ws[i] = Wg[i];
    if (tid < D_OUT) bs[tid] = bg[tid];

    int wave = tid >> 6;
    int lane = tid & 63;
    int sub  = lane >> 4;     // subgroup 0..3 (row offset within a 4-batch)
    int sl   = lane & 15;     // lane within subgroup: owns dims [8sl..8sl+7]
    int n = blockIdx.x * 8 + wave;       // 6250*8 == 50000 exactly

    // Preload deg + up to 48 neighbor indices per etype (lanes 0..47).
    int deg[N_ETYPES], idx[N_ETYPES];
    #pragma unroll
    for (int t = 0; t < N_ETYPES; t++) {
        int cell = t * N_NODES + n;
        int dg = cnt[cell];                       // wave-uniform
        int id = 0;
        if (lane < CAP1) id = bucket1[(long long)cell * CAP1 + lane];
        else if (lane < CAP1 + CAP2 && dg > CAP1)
            id = spill[(long long)cell * CAP2 + (lane - CAP1)];
        deg[t] = dg; idx[t] = id;
    }

    const uint4* fb4 = (const uint4*)featbf;   // row = 16 uint4 (256B)
    float s[8];
    #pragma unroll
    for (int k = 0; k < 8; k++) s[k] = 0.0f;

    #pragma unroll
    for (int t = 0; t < N_ETYPES; t++) {
        int d = (deg[t] < CAP1 + CAP2) ? deg[t] : (CAP1 + CAP2);
        float ax[8];
        #pragma unroll
        for (int k = 0; k < 8; k++) ax[k] = 0.0f;
        for (int j = 0; j < d; j += 4) {
            int row = j + sub;                       // may exceed d-1 by <=3
            int src = __shfl(idx[t], row);           // row<=50<64: safe; junk if row>=d
            uint4 p = fb4[(long long)src * 16 + sl]; // src>=0 always valid memory
            if (row < d) {
                ax[0] += __uint_as_float(p.x << 16);
                ax[1] += __uint_as_float(p.x & 0xffff0000u);
                ax[2] += __uint_as_float(p.y << 16);
                ax[3] += __uint_as_float(p.y & 0xffff0000u);
                ax[4] += __uint_as_float(p.z << 16);
                ax[5] += __uint_as_float(p.z & 0xffff0000u);
                ax[6] += __uint_as_float(p.w << 16);
                ax[7] += __uint_as_float(p.w & 0xffff0000u);
            }
        }
        // reduce the 4 subgroups (lanes l, l^16, l^32, l^48 hold partials of
        // the same dims) -- must complete BEFORE tanh(mean).
        #pragma unroll
        for (int k = 0; k < 8; k++) {
            ax[k] += __shfl_xor(ax[k], 16);
            ax[k] += __shfl_xor(ax[k], 32);
        }
        float inv = 1.0f / (float)((deg[t] > 0) ? deg[t] : 1);
        #pragma unroll
        for (int k = 0; k < 8; k++) s[k] += tanhf(ax[k] * inv);
    }

    // Epilogue: subgroup 0 (lanes 0..15) writes h for its 8 dims.
    if (sub == 0) {
        const float4* f4 = (const float4*)(feat + (long long)n * D_IN);
        float4 fa = f4[2 * sl];
        float4 fbv = f4[2 * sl + 1];
        float4 h0, h1;
        h0.x = tanhf(fa.x + 0.5f * s[0]);
        h0.y = tanhf(fa.y + 0.5f * s[1]);
        h0.z = tanhf(fa.z + 0.5f * s[2]);
        h0.w = tanhf(fa.w + 0.5f * s[3]);
        h1.x = tanhf(fbv.x + 0.5f * s[4]);
        h1.y = tanhf(fbv.y + 0.5f * s[5]);
        h1.z = tanhf(fbv.z + 0.5f * s[6]);
        h1.w = tanhf(fbv.w + 0.5f * s[7]);
        ((float4*)hs[wave])[2 * sl]     = h0;
        ((float4*)hs[wave])[2 * sl + 1] = h1;
    }
    __syncthreads();

    float acc = bs[lane];
    #pragma unroll 8
    for (int d = 0; d < D_IN; d++)
        acc += hs[wave][d] * Ws[d * D_OUT + lane];   // broadcast + stride-1: conflict-free
    out[(long long)n * D_OUT + lane] = acc;
}

extern "C" void kernel_launch(void* const* d_in, const int* in_sizes, int n_in,
                              void* d_out, int out_size, void* d_ws, size_t ws_size,
                              hipStream_t stream) {
    const float* feat = (const float*)d_in[0];
    const float* W    = (const float*)d_in[1];
    const float* b    = (const float*)d_in[2];
    const int* edge_index = (const int*)d_in[3];
    float* out = (float*)d_out;

    size_t featbf_bytes  = (size_t)N_NODES * D_IN * sizeof(unsigned short);          // 12.8 MB
    size_t bucket1_bytes = (size_t)N_ETYPES * N_NODES * CAP1 * sizeof(unsigned short); // 4.8 MB
    size_t spill_bytes   = (size_t)N_ETYPES * N_NODES * CAP2 * sizeof(unsigned short); // 9.6 MB
    size_t cnt_bytes     = (size_t)N_ETYPES * N_NODES * sizeof(int);                 // 0.6 MB
    if (ws_size < featbf_bytes + bucket1_bytes + spill_bytes + cnt_bytes)
        return;  // sentinel: out stays 0 (absmax would read 1.898)

    unsigned short* featbf  = (unsigned short*)d_ws;
    unsigned short* bucket1 = (unsigned short*)((char*)d_ws + featbf_bytes);
    unsigned short* spill   = (unsigned short*)((char*)d_ws + featbf_bytes + bucket1_bytes);
    int* cnt = (int*)((char*)d_ws + featbf_bytes + bucket1_bytes + spill_bytes);

    hipMemsetAsync(cnt, 0, cnt_bytes, stream);

    convert_kernel<<<(N_NODES * D_IN / 4) / 256, 256, 0, stream>>>(feat, featbf);

    fill_kernel<<<(N_EDGES + 255) / 256, 256, 0, stream>>>(edge_index, bucket1, spill, cnt);

    gather_linear_kernel<<<N_NODES / 8, 512, 0, stream>>>(
        feat, featbf, W, b, bucket1, spill, cnt, out);
}

// Round 7
// 261.570 us; speedup vs baseline: 1.4356x; 1.0783x over previous
//
#include <hip/hip_runtime.h>
#include <hip/hip_bf16.h>

#define N_NODES 50000
#define D_IN 128
#define D_OUT 64
#define N_ETYPES 3
#define E_PER_ETYPE 500000
#define N_EDGES (N_ETYPES * E_PER_ETYPE)
#define CAP1 16   // primary bucket: 32B (ushort) per cell
#define CAP2 32   // spill (deg>16: ~2.6% of cells; P(deg>48)~1e-19)

static __device__ __forceinline__ unsigned short f2bf(float f) {
    unsigned int x = __float_as_uint(f);
    unsigned int lsb = (x >> 16) & 1u;
    x += 0x7fffu + lsb;          // round-to-nearest-even
    return (unsigned short)(x >> 16);
}

// Branch-free tanh: v_mul, v_exp, v_add, v_rcp, v_fma  (~6 VALU vs ~35 for
// libm tanhf). Saturates correctly: x->-inf => exp->0 => 1-2*1 = -1;
// x->+inf => exp->inf => rcp->0 => +1. |err| ~ 1e-6, budget 0.038.
static __device__ __forceinline__ float fast_tanh(float x) {
    float e = __expf(2.0f * x);
    return 1.0f - 2.0f * __builtin_amdgcn_rcpf(e + 1.0f);
}

// feat (fp32) -> featbf (bf16), 4 elems/thread.
__global__ __launch_bounds__(256) void convert_kernel(
    const float* __restrict__ feat,
    unsigned short* __restrict__ featbf)
{
    int i = blockIdx.x * 256 + threadIdx.x;
    const float4* f4 = (const float4*)feat;
    float4 v = f4[i];
    ushort4 o;
    o.x = f2bf(v.x); o.y = f2bf(v.y); o.z = f2bf(v.z); o.w = f2bf(v.w);
    ((ushort4*)featbf)[i] = o;
}

// Flat one-pass binning (R3 structure, ushort payload). UNCHANGED from R6.
__global__ __launch_bounds__(256) void fill_kernel(
    const int* __restrict__ edge_index,
    unsigned short* __restrict__ bucket1,
    unsigned short* __restrict__ spill,
    int* __restrict__ cnt)
{
    int gid = blockIdx.x * 256 + threadIdx.x;
    if (gid >= N_EDGES) return;
    int t  = gid / E_PER_ETYPE;
    int ei = gid - t * E_PER_ETYPE;
    const int* base = edge_index + (long long)t * 2 * E_PER_ETYPE;
    int src = base[ei];                 // coalesced
    int dst = base[E_PER_ETYPE + ei];   // coalesced
    int cell = t * N_NODES + dst;
    int pos = atomicAdd(cnt + cell, 1);
    if (pos < CAP1)
        bucket1[(long long)cell * CAP1 + pos] = (unsigned short)src;
    else if (pos < CAP1 + CAP2)
        spill[(long long)cell * CAP2 + (pos - CAP1)] = (unsigned short)src;
}

// Fused gather + epilogue + linear. 512 thr = 8 waves = 8 nodes/block.
// Wave = 4 subgroups x 16 lanes; subgroup s reads row j+s as uint4 (8 bf16
// dims/lane) -> 4 independent 256B gathers in flight (R6: fixed latency).
// NEW (R7): tanh work distributed -- after the cross-subgroup reduce every
// lane has all 8 dim-sums; lane (sub,sl) now tanh's only dims
// {8sl+2sub, 8sl+2sub+1}: 8 fast_tanh/lane/node instead of 32 libm tanhf
// (R6 was VALU-bound at 94% on redundant transcendentals).
__global__ __launch_bounds__(512) void gather_linear_kernel(
    const float* __restrict__ feat,
    const unsigned short* __restrict__ featbf,
    const float* __restrict__ Wg,
    const float* __restrict__ bg,
    const unsigned short* __restrict__ bucket1,
    const unsigned short* __restrict__ spill,
    const int* __restrict__ cnt,
    float* __restrict__ out)
{
    __shared__ float Ws[D_IN * D_OUT];   // 32 KB
    __shared__ float bs[D_OUT];
    __shared__ float hs[8][D_IN];        // 4 KB

    int tid = threadIdx.x;
    for (int i = tid; i < D_IN * D_OUT; i += 512) Ws[i] = Wg[i];
    if (tid < D_OUT) bs[tid] = bg[tid];

    int wave = tid >> 6;
    int lane = tid & 63;
    int sub  = lane >> 4;     // subgroup 0..3
    int sl   = lane & 15;     // lane in subgroup: owns dims [8sl..8sl+7] for gather
    int n = blockIdx.x * 8 + wave;       // 6250*8 == 50000 exactly

    // Preload deg + up to 48 neighbor indices per etype (lanes 0..47).
    int deg[N_ETYPES], idx[N_ETYPES];
    #pragma unroll
    for (int t = 0; t < N_ETYPES; t++) {
        int cell = t * N_NODES + n;
        int dg = cnt[cell];                       // wave-uniform
        int id = 0;
        if (lane < CAP1) id = bucket1[(long long)cell * CAP1 + lane];
        else if (lane < CAP1 + CAP2 && dg > CAP1)
            id = spill[(long long)cell * CAP2 + (lane - CAP1)];
        deg[t] = dg; idx[t] = id;
    }

    const uint4* fb4 = (const uint4*)featbf;   // row = 16 uint4 (256B)
    // This lane's two owned dims (post-reduce): k0 = 2*sub, k0+1 of ax[8].
    int k0 = 2 * sub;
    float s0 = 0.0f, s1 = 0.0f;

    #pragma unroll
    for (int t = 0; t < N_ETYPES; t++) {
        int d = (deg[t] < CAP1 + CAP2) ? deg[t] : (CAP1 + CAP2);
        float ax[8];
        #pragma unroll
        for (int k = 0; k < 8; k++) ax[k] = 0.0f;
        for (int j = 0; j < d; j += 4) {
            int row = j + sub;                       // may exceed d-1 by <=3
            int src = __shfl(idx[t], row);           // row<=50<64: safe
            uint4 p = fb4[(long long)src * 16 + sl]; // always valid memory
            if (row < d) {
                ax[0] += __uint_as_float(p.x << 16);
                ax[1] += __uint_as_float(p.x & 0xffff0000u);
                ax[2] += __uint_as_float(p.y << 16);
                ax[3] += __uint_as_float(p.y & 0xffff0000u);
                ax[4] += __uint_as_float(p.z << 16);
                ax[5] += __uint_as_float(p.z & 0xffff0000u);
                ax[6] += __uint_as_float(p.w << 16);
                ax[7] += __uint_as_float(p.w & 0xffff0000u);
            }
        }
        // Cross-subgroup reduce: lanes l, l^16, l^32, l^48 hold partials of
        // the same 8 dims. After this every lane has the full sums.
        #pragma unroll
        for (int k = 0; k < 8; k++) {
            ax[k] += __shfl_xor(ax[k], 16);
            ax[k] += __shfl_xor(ax[k], 32);
        }
        float inv = 1.0f / (float)((deg[t] > 0) ? deg[t] : 1);
        // Only this lane's 2 owned dims get the transcendental.
        s0 += fast_tanh(ax[k0]     * inv);
        s1 += fast_tanh(ax[k0 + 1] * inv);
    }

    // Epilogue: lane (sub,sl) owns dims D0=8sl+2sub, D0+1 -> float2 index
    // 4sl+sub (a lane permutation covering 0..63: still one 512B wave access).
    int p2 = 4 * sl + sub;
    float2 f = ((const float2*)feat)[(long long)n * 64 + p2];
    float2 hv;
    hv.x = fast_tanh(f.x + 0.5f * s0);
    hv.y = fast_tanh(f.y + 0.5f * s1);
    ((float2*)hs[wave])[p2] = hv;
    __syncthreads();

    float acc = bs[lane];
    #pragma unroll 8
    for (int d = 0; d < D_IN; d++)
        acc += hs[wave][d] * Ws[d * D_OUT + lane];   // broadcast + stride-1: conflict-free
    out[(long long)n * D_OUT + lane] = acc;
}

extern "C" void kernel_launch(void* const* d_in, const int* in_sizes, int n_in,
                              void* d_out, int out_size, void* d_ws, size_t ws_size,
                              hipStream_t stream) {
    const float* feat = (const float*)d_in[0];
    const float* W    = (const float*)d_in[1];
    const float* b    = (const float*)d_in[2];
    const int* edge_index = (const int*)d_in[3];
    float* out = (float*)d_out;

    size_t featbf_bytes  = (size_t)N_NODES * D_IN * sizeof(unsigned short);            // 12.8 MB
    size_t bucket1_bytes = (size_t)N_ETYPES * N_NODES * CAP1 * sizeof(unsigned short); //  4.8 MB
    size_t spill_bytes   = (size_t)N_ETYPES * N_NODES * CAP2 * sizeof(unsigned short); //  9.6 MB
    size_t cnt_bytes     = (size_t)N_ETYPES * N_NODES * sizeof(int);                   //  0.6 MB
    if (ws_size < featbf_bytes + bucket1_bytes + spill_bytes + cnt_bytes)
        return;  // sentinel: out stays 0 (absmax would read 1.898)

    unsigned short* featbf  = (unsigned short*)d_ws;
    unsigned short* bucket1 = (unsigned short*)((char*)d_ws + featbf_bytes);
    unsigned short* spill   = (unsigned short*)((char*)d_ws + featbf_bytes + bucket1_bytes);
    int* cnt = (int*)((char*)d_ws + featbf_bytes + bucket1_bytes + spill_bytes);

    hipMemsetAsync(cnt, 0, cnt_bytes, stream);

    convert_kernel<<<(N_NODES * D_IN / 4) / 256, 256, 0, stream>>>(feat, featbf);

    fill_kernel<<<(N_EDGES + 255) / 256, 256, 0, stream>>>(edge_index, bucket1, spill, cnt);

    gather_linear_kernel<<<N_NODES / 8, 512, 0, stream>>>(
        feat, featbf, W, b, bucket1, spill, cnt, out);
}